// Round 1
// baseline (55.790 us; speedup 1.0000x reference)
//
#include <hip/hip_runtime.h>
#include <math.h>

#define STEPN 16

// ---- monotone key transform so uint atomics give float min/max ----
__device__ __forceinline__ unsigned f2key(float f) {
    unsigned u = __float_as_uint(f);
    return u ^ ((u >> 31) ? 0xFFFFFFFFu : 0x80000000u);
}
__device__ __forceinline__ float key2f(unsigned k) {
    unsigned u = (k >> 31) ? (k ^ 0x80000000u) : ~k;
    return __uint_as_float(u);
}

__global__ void pe_init_ws(unsigned* ws) {
    if (threadIdx.x == 0 && blockIdx.x == 0) {
        ws[0] = 0xFFFFFFFFu; // running min key
        ws[1] = 0u;          // running max key
    }
}

__global__ void pe_minmax(const float4* __restrict__ in4, int n4, unsigned* __restrict__ ws) {
    int gid = blockIdx.x * blockDim.x + threadIdx.x;
    unsigned kmin = 0xFFFFFFFFu, kmax = 0u;
    if (gid < n4) {
        float4 v = in4[gid];
        unsigned a = f2key(v.x), b = f2key(v.y), c = f2key(v.z), d = f2key(v.w);
        kmin = min(min(a, b), min(c, d));
        kmax = max(max(a, b), max(c, d));
    }
    // wave64 butterfly reduce
    #pragma unroll
    for (int off = 32; off > 0; off >>= 1) {
        kmin = min(kmin, (unsigned)__shfl_down((int)kmin, off, 64));
        kmax = max(kmax, (unsigned)__shfl_down((int)kmax, off, 64));
    }
    __shared__ unsigned smin[4], smax[4];
    int lane = threadIdx.x & 63, wid = threadIdx.x >> 6;
    if (lane == 0) { smin[wid] = kmin; smax[wid] = kmax; }
    __syncthreads();
    if (threadIdx.x == 0) {
        unsigned m0 = smin[0], M0 = smax[0];
        for (int w = 1; w < (int)(blockDim.x >> 6); ++w) {
            m0 = min(m0, smin[w]); M0 = max(M0, smax[w]);
        }
        atomicMin(&ws[0], m0);
        atomicMax(&ws[1], M0);
    }
}

// Each thread: one pop-neuron x 4 consecutive elements. Element index is the
// fast axis across threads -> every float4 store is wave-coalesced.
__global__ void pe_main(const float4* __restrict__ in4,
                        const unsigned* __restrict__ ws,
                        const float* __restrict__ vth_p,
                        float* __restrict__ out,
                        int n_elem, int m) {
    const int n4 = n_elem >> 2;
    const int gid = blockIdx.x * blockDim.x + threadIdx.x;
    if (gid >= m * n4) return;
    const int neuron = gid / n4;
    const int e4 = gid - neuron * n4;

    const float Imin = key2f(ws[0]);
    const float Imax = key2f(ws[1]);
    const float VTH  = *vth_p;

    // Replicate numpy fp32 rounding exactly: no FMA contraction.
    const float span  = __fdiv_rn(__fsub_rn(Imax, Imin), (float)(m - 2));
    const float c     = (float)(2 * neuron - 3) * 0.5f;           // exact
    const float mu    = __fadd_rn(Imin, __fmul_rn(c, span));
    const float sigma = __fdiv_rn(span, 1.5f);
    const float denom = __fmul_rn(__fmul_rn(2.0f, sigma), sigma); // (2*sigma)*sigma

    float4 x = in4[e4];
    float xs[4] = {x.x, x.y, x.z, x.w};
    float dv[4];
    #pragma unroll
    for (int j = 0; j < 4; ++j) {
        float d = __fsub_rn(xs[j], mu);
        float q = __fdiv_rn(__fmul_rn(d, d), denom);
        // correctly-rounded fp32 exp via double
        dv[j] = (float)exp(-(double)q);
    }

    float v[4]   = {0.f, 0.f, 0.f, 0.f};
    float cnt[4] = {0.f, 0.f, 0.f, 0.f};
    const size_t plane = (size_t)n_elem;
    float4* out4 = (float4*)out;
    const size_t e4base = (size_t)e4; // float4 units within a plane

    #pragma unroll
    for (int t = 0; t < STEPN; ++t) {
        float4 s4;
        float* sp = &s4.x;
        #pragma unroll
        for (int j = 0; j < 4; ++j) {
            v[j] = __fadd_rn(v[j], dv[j]);
            float s = (v[j] >= VTH) ? 1.0f : 0.0f;
            v[j] = __fsub_rn(v[j], s * VTH);   // s*VTH exact (s in {0,1})
            sp[j] = s;
            cnt[j] += s;
        }
        out4[(((size_t)t * m + neuron) * plane >> 2) + e4base] = s4;
    }

    const float inv = 1.0f / (float)STEPN;     // 1/16 exact
    float4 r4 = {cnt[0] * inv, cnt[1] * inv, cnt[2] * inv, cnt[3] * inv};
    out4[(((size_t)STEPN * m + neuron) * plane >> 2) + e4base] = r4;
}

extern "C" void kernel_launch(void* const* d_in, const int* in_sizes, int n_in,
                              void* d_out, int out_size, void* d_ws, size_t ws_size,
                              hipStream_t stream) {
    const float* inp = (const float*)d_in[0];
    const float* vth = (const float*)d_in[1];
    // d_in[2] is num_popneurons on device; derive m from sizes instead
    const int n_elem = in_sizes[0];                 // 1024*256 = 262144
    const int m = out_size / ((STEPN + 1) * n_elem); // 10
    const int n4 = n_elem >> 2;

    unsigned* ws = (unsigned*)d_ws;
    float* out = (float*)d_out;

    pe_init_ws<<<1, 64, 0, stream>>>(ws);

    int rblocks = (n4 + 255) / 256;
    pe_minmax<<<rblocks, 256, 0, stream>>>((const float4*)inp, n4, ws);

    int total = m * n4;
    int mblocks = (total + 255) / 256;
    pe_main<<<mblocks, 256, 0, stream>>>((const float4*)inp, ws, vth, out, n_elem, m);
}

// Round 2
// 50.012 us; speedup vs baseline: 1.1155x; 1.1155x over previous
//
#include <hip/hip_runtime.h>
#include <math.h>

#define STEPN 16

typedef float v4f __attribute__((ext_vector_type(4)));

// ---- monotone key transform so uint atomics give float min/max ----
// max is stored INVERTED (~key) so both reductions are atomicMin and the
// init is a single memset(0xFF).
__device__ __forceinline__ unsigned f2key(float f) {
    unsigned u = __float_as_uint(f);
    return u ^ ((u >> 31) ? 0xFFFFFFFFu : 0x80000000u);
}
__device__ __forceinline__ float key2f(unsigned k) {
    unsigned u = (k >> 31) ? (k ^ 0x80000000u) : ~k;
    return __uint_as_float(u);
}

__global__ void pe_minmax(const v4f* __restrict__ in4, int n4, unsigned* __restrict__ ws) {
    int gid = blockIdx.x * blockDim.x + threadIdx.x;
    unsigned kmin = 0xFFFFFFFFu, kimax = 0xFFFFFFFFu; // kimax = ~maxkey
    if (gid < n4) {
        v4f v = in4[gid];
        unsigned a = f2key(v.x), b = f2key(v.y), c = f2key(v.z), d = f2key(v.w);
        kmin  = min(min(a, b), min(c, d));
        kimax = ~max(max(a, b), max(c, d));
    }
    #pragma unroll
    for (int off = 32; off > 0; off >>= 1) {
        kmin  = min(kmin,  (unsigned)__shfl_down((int)kmin,  off, 64));
        kimax = min(kimax, (unsigned)__shfl_down((int)kimax, off, 64));
    }
    __shared__ unsigned sm[8];
    int lane = threadIdx.x & 63, wid = threadIdx.x >> 6;
    if (lane == 0) { sm[wid * 2] = kmin; sm[wid * 2 + 1] = kimax; }
    __syncthreads();
    if (threadIdx.x == 0) {
        unsigned a = sm[0], b = sm[1];
        for (int w = 1; w < (int)(blockDim.x >> 6); ++w) {
            a = min(a, sm[w * 2]); b = min(b, sm[w * 2 + 1]);
        }
        atomicMin(&ws[0], a);
        atomicMin(&ws[1], b);
    }
}

// 8 elements per thread, split-quad layout: lane i of a wave owns float4
// indices (waveBase + i) and (waveBase + 64 + i), so every store instruction
// is 64 contiguous float4 = 1 KB. 1280 blocks -> 20 waves/CU, fully resident.
__global__ __launch_bounds__(256) void pe_main(
        const v4f* __restrict__ in4,
        const unsigned* __restrict__ ws,
        const float* __restrict__ vth_p,
        float* __restrict__ out,
        int n_elem, int m)
{
    const int n4  = n_elem >> 2;        // float4 per plane (65536)
    const int wpp = n4 >> 7;            // waves per plane: 128 float4/wave (512)
    const int gid  = blockIdx.x * blockDim.x + threadIdx.x;
    const int wave = gid >> 6;
    const int lane = gid & 63;
    if (wave >= m * wpp) return;
    const int neuron = wave / wpp;
    const int lw     = wave - neuron * wpp;
    const int fA = (lw << 7) + lane;    // float4 idx within plane
    const int fB = fA + 64;

    const float Imin = key2f(ws[0]);
    const float Imax = key2f(~ws[1]);
    const float VTH  = *vth_p;

    // Replicate numpy fp32 rounding exactly: no FMA contraction.
    const float span  = __fdiv_rn(__fsub_rn(Imax, Imin), (float)(m - 2));
    const float c     = (float)(2 * neuron - 3) * 0.5f;            // exact
    const float mu    = __fadd_rn(Imin, __fmul_rn(c, span));
    const float sigma = __fdiv_rn(span, 1.5f);
    const float denom = __fmul_rn(__fmul_rn(2.0f, sigma), sigma);  // (2*sigma)*sigma

    v4f xa = in4[fA], xb = in4[fB];
    float xs[8] = {xa.x, xa.y, xa.z, xa.w, xb.x, xb.y, xb.z, xb.w};
    float dv[8];
    #pragma unroll
    for (int j = 0; j < 8; ++j) {
        float d = __fsub_rn(xs[j], mu);
        float q = __fdiv_rn(__fmul_rn(d, d), denom);
        // correctly-rounded fp32 exp via double (matches np.exp float32)
        dv[j] = (float)exp(-(double)q);
    }

    float v[8]   = {0.f,0.f,0.f,0.f,0.f,0.f,0.f,0.f};
    float cnt[8] = {0.f,0.f,0.f,0.f,0.f,0.f,0.f,0.f};

    v4f* outp = (v4f*)out + (size_t)neuron * n4 + fA;
    const size_t tstride = (size_t)m * n4;

    #pragma unroll
    for (int t = 0; t < STEPN; ++t) {
        v4f sa, sb;
        #pragma unroll
        for (int j = 0; j < 4; ++j) {
            v[j] = __fadd_rn(v[j], dv[j]);
            float s = (v[j] >= VTH) ? 1.0f : 0.0f;
            v[j] = __fsub_rn(v[j], s * VTH);   // s*VTH exact (s in {0,1})
            sa[j] = s;
            cnt[j] += s;
        }
        #pragma unroll
        for (int j = 4; j < 8; ++j) {
            v[j] = __fadd_rn(v[j], dv[j]);
            float s = (v[j] >= VTH) ? 1.0f : 0.0f;
            v[j] = __fsub_rn(v[j], s * VTH);
            sb[j - 4] = s;
            cnt[j] += s;
        }
        __builtin_nontemporal_store(sa, outp);
        __builtin_nontemporal_store(sb, outp + 64);
        outp += tstride;
    }

    const float inv = 1.0f / (float)STEPN;   // exact
    v4f ra, rb;
    #pragma unroll
    for (int j = 0; j < 4; ++j) { ra[j] = cnt[j] * inv; rb[j] = cnt[j + 4] * inv; }
    __builtin_nontemporal_store(ra, outp);
    __builtin_nontemporal_store(rb, outp + 64);
}

extern "C" void kernel_launch(void* const* d_in, const int* in_sizes, int n_in,
                              void* d_out, int out_size, void* d_ws, size_t ws_size,
                              hipStream_t stream) {
    const float* inp = (const float*)d_in[0];
    const float* vth = (const float*)d_in[1];
    const int n_elem = in_sizes[0];                  // 262144
    const int m = out_size / ((STEPN + 1) * n_elem); // 10
    const int n4 = n_elem >> 2;

    unsigned* ws = (unsigned*)d_ws;
    float* out = (float*)d_out;

    // init both running-min keys (min and inverted-max) to 0xFFFFFFFF
    hipMemsetAsync(ws, 0xFF, 8, stream);

    int rblocks = (n4 + 255) / 256;
    pe_minmax<<<rblocks, 256, 0, stream>>>((const v4f*)inp, n4, ws);

    int total_threads = m * (n4 >> 7) * 64;          // m * waves/plane * 64
    int mblocks = (total_threads + 255) / 256;
    pe_main<<<mblocks, 256, 0, stream>>>((const v4f*)inp, ws, vth, out, n_elem, m);
}

// Round 3
// 44.238 us; speedup vs baseline: 1.2611x; 1.1305x over previous
//
#include <hip/hip_runtime.h>
#include <math.h>

#define STEPN 16

typedef float v4f __attribute__((ext_vector_type(4)));

// ---- monotone key transform so uint atomics give float min/max ----
// max is stored INVERTED (~key) so both reductions are atomicMin and the
// init is a single memset(0xFF).
__device__ __forceinline__ unsigned f2key(float f) {
    unsigned u = __float_as_uint(f);
    return u ^ ((u >> 31) ? 0xFFFFFFFFu : 0x80000000u);
}
__device__ __forceinline__ float key2f(unsigned k) {
    unsigned u = (k >> 31) ? (k ^ 0x80000000u) : ~k;
    return __uint_as_float(u);
}

__global__ void pe_minmax(const v4f* __restrict__ in4, int n4, unsigned* __restrict__ ws) {
    int gid = blockIdx.x * blockDim.x + threadIdx.x;
    unsigned kmin = 0xFFFFFFFFu, kimax = 0xFFFFFFFFu; // kimax = ~maxkey
    if (gid < n4) {
        v4f v = in4[gid];
        unsigned a = f2key(v.x), b = f2key(v.y), c = f2key(v.z), d = f2key(v.w);
        kmin  = min(min(a, b), min(c, d));
        kimax = ~max(max(a, b), max(c, d));
    }
    #pragma unroll
    for (int off = 32; off > 0; off >>= 1) {
        kmin  = min(kmin,  (unsigned)__shfl_down((int)kmin,  off, 64));
        kimax = min(kimax, (unsigned)__shfl_down((int)kimax, off, 64));
    }
    __shared__ unsigned sm[8];
    int lane = threadIdx.x & 63, wid = threadIdx.x >> 6;
    if (lane == 0) { sm[wid * 2] = kmin; sm[wid * 2 + 1] = kimax; }
    __syncthreads();
    if (threadIdx.x == 0) {
        unsigned a = sm[0], b = sm[1];
        for (int w = 1; w < (int)(blockDim.x >> 6); ++w) {
            a = min(a, sm[w * 2]); b = min(b, sm[w * 2 + 1]);
        }
        atomicMin(&ws[0], a);
        atomicMin(&ws[1], b);
    }
}

// 8 elements per thread, split-quad layout: lane i of a wave owns float4
// indices (waveBase + i) and (waveBase + 64 + i), so every store instruction
// is 64 contiguous float4 = 1 KB. 1280 blocks -> 20 waves/CU, fully resident.
// R3 A/B: plain stores instead of nontemporal (fill kernel evidence: plain
// stores sustain 6.8 TB/s on this buffer).
__global__ __launch_bounds__(256) void pe_main(
        const v4f* __restrict__ in4,
        const unsigned* __restrict__ ws,
        const float* __restrict__ vth_p,
        float* __restrict__ out,
        int n_elem, int m)
{
    const int n4  = n_elem >> 2;        // float4 per plane (65536)
    const int wpp = n4 >> 7;            // waves per plane: 128 float4/wave (512)
    const int gid  = blockIdx.x * blockDim.x + threadIdx.x;
    const int wave = gid >> 6;
    const int lane = gid & 63;
    if (wave >= m * wpp) return;
    const int neuron = wave / wpp;
    const int lw     = wave - neuron * wpp;
    const int fA = (lw << 7) + lane;    // float4 idx within plane
    const int fB = fA + 64;

    const float Imin = key2f(ws[0]);
    const float Imax = key2f(~ws[1]);
    const float VTH  = *vth_p;

    // Replicate numpy fp32 rounding exactly: no FMA contraction.
    const float span  = __fdiv_rn(__fsub_rn(Imax, Imin), (float)(m - 2));
    const float c     = (float)(2 * neuron - 3) * 0.5f;            // exact
    const float mu    = __fadd_rn(Imin, __fmul_rn(c, span));
    const float sigma = __fdiv_rn(span, 1.5f);
    const float denom = __fmul_rn(__fmul_rn(2.0f, sigma), sigma);  // (2*sigma)*sigma

    v4f xa = in4[fA], xb = in4[fB];
    float xs[8] = {xa.x, xa.y, xa.z, xa.w, xb.x, xb.y, xb.z, xb.w};
    float dv[8];
    #pragma unroll
    for (int j = 0; j < 8; ++j) {
        float d = __fsub_rn(xs[j], mu);
        float q = __fdiv_rn(__fmul_rn(d, d), denom);
        // correctly-rounded fp32 exp via double (matches np.exp float32)
        dv[j] = (float)exp(-(double)q);
    }

    float v[8]   = {0.f,0.f,0.f,0.f,0.f,0.f,0.f,0.f};
    float cnt[8] = {0.f,0.f,0.f,0.f,0.f,0.f,0.f,0.f};

    v4f* outp = (v4f*)out + (size_t)neuron * n4 + fA;
    const size_t tstride = (size_t)m * n4;

    #pragma unroll
    for (int t = 0; t < STEPN; ++t) {
        v4f sa, sb;
        #pragma unroll
        for (int j = 0; j < 4; ++j) {
            v[j] = __fadd_rn(v[j], dv[j]);
            float s = (v[j] >= VTH) ? 1.0f : 0.0f;
            v[j] = __fsub_rn(v[j], s * VTH);   // s*VTH exact (s in {0,1})
            sa[j] = s;
            cnt[j] += s;
        }
        #pragma unroll
        for (int j = 4; j < 8; ++j) {
            v[j] = __fadd_rn(v[j], dv[j]);
            float s = (v[j] >= VTH) ? 1.0f : 0.0f;
            v[j] = __fsub_rn(v[j], s * VTH);
            sb[j - 4] = s;
            cnt[j] += s;
        }
        outp[0]  = sa;
        outp[64] = sb;
        outp += tstride;
    }

    const float inv = 1.0f / (float)STEPN;   // exact
    v4f ra, rb;
    #pragma unroll
    for (int j = 0; j < 4; ++j) { ra[j] = cnt[j] * inv; rb[j] = cnt[j + 4] * inv; }
    outp[0]  = ra;
    outp[64] = rb;
}

extern "C" void kernel_launch(void* const* d_in, const int* in_sizes, int n_in,
                              void* d_out, int out_size, void* d_ws, size_t ws_size,
                              hipStream_t stream) {
    const float* inp = (const float*)d_in[0];
    const float* vth = (const float*)d_in[1];
    const int n_elem = in_sizes[0];                  // 262144
    const int m = out_size / ((STEPN + 1) * n_elem); // 10
    const int n4 = n_elem >> 2;

    unsigned* ws = (unsigned*)d_ws;
    float* out = (float*)d_out;

    // init both running-min keys (min and inverted-max) to 0xFFFFFFFF
    hipMemsetAsync(ws, 0xFF, 8, stream);

    int rblocks = (n4 + 255) / 256;
    pe_minmax<<<rblocks, 256, 0, stream>>>((const v4f*)inp, n4, ws);

    int total_threads = m * (n4 >> 7) * 64;          // m * waves/plane * 64
    int mblocks = (total_threads + 255) / 256;
    pe_main<<<mblocks, 256, 0, stream>>>((const v4f*)inp, ws, vth, out, n_elem, m);
}

// Round 4
// 43.621 us; speedup vs baseline: 1.2790x; 1.0141x over previous
//
#include <hip/hip_runtime.h>
#include <math.h>

#define STEPN 16

typedef float v4f __attribute__((ext_vector_type(4)));

// ---- monotone key transform so uint atomics give float min/max ----
// max is stored INVERTED (~key) so both reductions are atomicMin and the
// init is a single memset(0xFF).
__device__ __forceinline__ unsigned f2key(float f) {
    unsigned u = __float_as_uint(f);
    return u ^ ((u >> 31) ? 0xFFFFFFFFu : 0x80000000u);
}
__device__ __forceinline__ float key2f(unsigned k) {
    unsigned u = (k >> 31) ? (k ^ 0x80000000u) : ~k;
    return __uint_as_float(u);
}

__global__ void pe_minmax(const v4f* __restrict__ in4, int n4, unsigned* __restrict__ ws) {
    int gid = blockIdx.x * blockDim.x + threadIdx.x;
    unsigned kmin = 0xFFFFFFFFu, kimax = 0xFFFFFFFFu; // kimax = ~maxkey
    if (gid < n4) {
        v4f v = in4[gid];
        unsigned a = f2key(v.x), b = f2key(v.y), c = f2key(v.z), d = f2key(v.w);
        kmin  = min(min(a, b), min(c, d));
        kimax = ~max(max(a, b), max(c, d));
    }
    #pragma unroll
    for (int off = 32; off > 0; off >>= 1) {
        kmin  = min(kmin,  (unsigned)__shfl_down((int)kmin,  off, 64));
        kimax = min(kimax, (unsigned)__shfl_down((int)kimax, off, 64));
    }
    __shared__ unsigned sm[8];
    int lane = threadIdx.x & 63, wid = threadIdx.x >> 6;
    if (lane == 0) { sm[wid * 2] = kmin; sm[wid * 2 + 1] = kimax; }
    __syncthreads();
    if (threadIdx.x == 0) {
        unsigned a = sm[0], b = sm[1];
        for (int w = 1; w < (int)(blockDim.x >> 6); ++w) {
            a = min(a, sm[w * 2]); b = min(b, sm[w * 2 + 1]);
        }
        atomicMin(&ws[0], a);
        atomicMin(&ws[1], b);
    }
}

// 8 elements per thread, split-quad layout: lane i of a wave owns float4
// indices (waveBase + i) and (waveBase + 64 + i), so every store instruction
// is 64 contiguous float4 = 1 KB. Grid = 5120 waves = 20 waves/CU.
// R4: __launch_bounds__(256,5) caps VGPR at ~102 so all 20 waves/CU are
// resident in ONE round (no scheduling tail on a drain-limited kernel);
// t-loop unroll limited to 4 to keep live store payloads small.
__global__ __launch_bounds__(256, 5) void pe_main(
        const v4f* __restrict__ in4,
        const unsigned* __restrict__ ws,
        const float* __restrict__ vth_p,
        float* __restrict__ out,
        int n_elem, int m)
{
    const int n4  = n_elem >> 2;        // float4 per plane (65536)
    const int wpp = n4 >> 7;            // waves per plane: 128 float4/wave (512)
    const int gid  = blockIdx.x * blockDim.x + threadIdx.x;
    const int wave = gid >> 6;
    const int lane = gid & 63;
    if (wave >= m * wpp) return;
    const int neuron = wave / wpp;
    const int lw     = wave - neuron * wpp;
    const int fA = (lw << 7) + lane;    // float4 idx within plane
    const int fB = fA + 64;

    const float Imin = key2f(ws[0]);
    const float Imax = key2f(~ws[1]);
    const float VTH  = *vth_p;

    // Replicate numpy fp32 rounding exactly: no FMA contraction.
    const float span  = __fdiv_rn(__fsub_rn(Imax, Imin), (float)(m - 2));
    const float c     = (float)(2 * neuron - 3) * 0.5f;            // exact
    const float mu    = __fadd_rn(Imin, __fmul_rn(c, span));
    const float sigma = __fdiv_rn(span, 1.5f);
    const float denom = __fmul_rn(__fmul_rn(2.0f, sigma), sigma);  // (2*sigma)*sigma

    v4f xa = in4[fA], xb = in4[fB];
    float xs[8] = {xa.x, xa.y, xa.z, xa.w, xb.x, xb.y, xb.z, xb.w};
    float dv[8];
    #pragma unroll
    for (int j = 0; j < 8; ++j) {
        float d = __fsub_rn(xs[j], mu);
        float q = __fdiv_rn(__fmul_rn(d, d), denom);
        // correctly-rounded fp32 exp via double (matches np.exp float32)
        dv[j] = (float)exp(-(double)q);
    }

    float v[8]   = {0.f,0.f,0.f,0.f,0.f,0.f,0.f,0.f};
    float cnt[8] = {0.f,0.f,0.f,0.f,0.f,0.f,0.f,0.f};

    v4f* outp = (v4f*)out + (size_t)neuron * n4 + fA;
    const size_t tstride = (size_t)m * n4;

    #pragma unroll 4
    for (int t = 0; t < STEPN; ++t) {
        v4f sa, sb;
        #pragma unroll
        for (int j = 0; j < 4; ++j) {
            v[j] = __fadd_rn(v[j], dv[j]);
            float s = (v[j] >= VTH) ? 1.0f : 0.0f;
            v[j] = __fsub_rn(v[j], s * VTH);   // s*VTH exact (s in {0,1})
            sa[j] = s;
            cnt[j] += s;
        }
        #pragma unroll
        for (int j = 4; j < 8; ++j) {
            v[j] = __fadd_rn(v[j], dv[j]);
            float s = (v[j] >= VTH) ? 1.0f : 0.0f;
            v[j] = __fsub_rn(v[j], s * VTH);
            sb[j - 4] = s;
            cnt[j] += s;
        }
        outp[0]  = sa;
        outp[64] = sb;
        outp += tstride;
    }

    const float inv = 1.0f / (float)STEPN;   // exact
    v4f ra, rb;
    #pragma unroll
    for (int j = 0; j < 4; ++j) { ra[j] = cnt[j] * inv; rb[j] = cnt[j + 4] * inv; }
    outp[0]  = ra;
    outp[64] = rb;
}

extern "C" void kernel_launch(void* const* d_in, const int* in_sizes, int n_in,
                              void* d_out, int out_size, void* d_ws, size_t ws_size,
                              hipStream_t stream) {
    const float* inp = (const float*)d_in[0];
    const float* vth = (const float*)d_in[1];
    const int n_elem = in_sizes[0];                  // 262144
    const int m = out_size / ((STEPN + 1) * n_elem); // 10
    const int n4 = n_elem >> 2;

    unsigned* ws = (unsigned*)d_ws;
    float* out = (float*)d_out;

    // init both running-min keys (min and inverted-max) to 0xFFFFFFFF
    hipMemsetAsync(ws, 0xFF, 8, stream);

    int rblocks = (n4 + 255) / 256;
    pe_minmax<<<rblocks, 256, 0, stream>>>((const v4f*)inp, n4, ws);

    int total_threads = m * (n4 >> 7) * 64;          // m * waves/plane * 64
    int mblocks = (total_threads + 255) / 256;
    pe_main<<<mblocks, 256, 0, stream>>>((const v4f*)inp, ws, vth, out, n_elem, m);
}

// Round 5
// 36.900 us; speedup vs baseline: 1.5119x; 1.1821x over previous
//
#include <hip/hip_runtime.h>
#include <math.h>

#define STEPN 16

typedef float v4f __attribute__((ext_vector_type(4)));

// ---- monotone key transform: uint min on keys == float min; max stored
// as inverted key so both partials reduce with min. No atomics anywhere.
__device__ __forceinline__ unsigned f2key(float f) {
    unsigned u = __float_as_uint(f);
    return u ^ ((u >> 31) ? 0xFFFFFFFFu : 0x80000000u);
}
__device__ __forceinline__ float key2f(unsigned k) {
    unsigned u = (k >> 31) ? (k ^ 0x80000000u) : ~k;
    return __uint_as_float(u);
}

// 256 blocks x 256 threads, 1 float4/thread. Per-block partial min / ~max
// written as plain stores to ws[2b], ws[2b+1] -> no memset node, no atomic
// contention, deterministic (fully rewritten every call).
__global__ __launch_bounds__(256) void pe_minmax_part(const v4f* __restrict__ in4,
                                                      unsigned* __restrict__ ws) {
    int gid = blockIdx.x * blockDim.x + threadIdx.x;
    v4f v = in4[gid];
    unsigned a = f2key(v.x), b = f2key(v.y), c = f2key(v.z), d = f2key(v.w);
    unsigned kmin  = min(min(a, b), min(c, d));
    unsigned kimax = ~max(max(a, b), max(c, d));
    #pragma unroll
    for (int off = 32; off > 0; off >>= 1) {
        kmin  = min(kmin,  (unsigned)__shfl_down((int)kmin,  off, 64));
        kimax = min(kimax, (unsigned)__shfl_down((int)kimax, off, 64));
    }
    __shared__ unsigned sm[8];
    int lane = threadIdx.x & 63, wid = threadIdx.x >> 6;
    if (lane == 0) { sm[wid * 2] = kmin; sm[wid * 2 + 1] = kimax; }
    __syncthreads();
    if (threadIdx.x == 0) {
        unsigned a0 = sm[0], b0 = sm[1];
        #pragma unroll
        for (int w = 1; w < 4; ++w) { a0 = min(a0, sm[w * 2]); b0 = min(b0, sm[w * 2 + 1]); }
        ws[blockIdx.x * 2]     = a0;
        ws[blockIdx.x * 2 + 1] = b0;
    }
}

// 8 elements per thread, split-quad layout: lane i of a wave owns float4
// indices (waveBase + i) and (waveBase + 64 + i) -> every store is 64
// contiguous float4 = 1 KB. Grid = 1280 blocks = 20 waves/CU.
// Prologue: reduce the np partial pairs (2 KB, L2-hit) and broadcast.
__global__ __launch_bounds__(256, 5) void pe_main(
        const v4f* __restrict__ in4,
        const unsigned* __restrict__ ws,
        const float* __restrict__ vth_p,
        float* __restrict__ out,
        int n_elem, int m, int np)
{
    // ---- block-local reduction of partials ----
    unsigned kmin = 0xFFFFFFFFu, kimax = 0xFFFFFFFFu;
    for (int i = threadIdx.x; i < np; i += 256) {
        kmin  = min(kmin,  ws[2 * i]);
        kimax = min(kimax, ws[2 * i + 1]);
    }
    #pragma unroll
    for (int off = 32; off > 0; off >>= 1) {
        kmin  = min(kmin,  (unsigned)__shfl_down((int)kmin,  off, 64));
        kimax = min(kimax, (unsigned)__shfl_down((int)kimax, off, 64));
    }
    __shared__ unsigned sred[8];
    __shared__ float sval[2];
    {
        int lane = threadIdx.x & 63, wid = threadIdx.x >> 6;
        if (lane == 0) { sred[wid * 2] = kmin; sred[wid * 2 + 1] = kimax; }
    }
    __syncthreads();
    if (threadIdx.x == 0) {
        unsigned a0 = sred[0], b0 = sred[1];
        #pragma unroll
        for (int w = 1; w < 4; ++w) { a0 = min(a0, sred[w * 2]); b0 = min(b0, sred[w * 2 + 1]); }
        sval[0] = key2f(a0);
        sval[1] = key2f(~b0);
    }
    __syncthreads();
    const float Imin = sval[0];
    const float Imax = sval[1];

    const int n4  = n_elem >> 2;        // float4 per plane (65536)
    const int wpp = n4 >> 7;            // waves per plane (512)
    const int gid  = blockIdx.x * blockDim.x + threadIdx.x;
    const int wave = gid >> 6;
    const int lane = gid & 63;
    if (wave >= m * wpp) return;        // grid is exact; guard is belt+braces
    const int neuron = wave / wpp;
    const int lw     = wave - neuron * wpp;
    const int fA = (lw << 7) + lane;
    const int fB = fA + 64;

    const float VTH = *vth_p;

    // Replicate numpy fp32 rounding exactly: no FMA contraction.
    const float span  = __fdiv_rn(__fsub_rn(Imax, Imin), (float)(m - 2));
    const float c     = (float)(2 * neuron - 3) * 0.5f;            // exact
    const float mu    = __fadd_rn(Imin, __fmul_rn(c, span));
    const float sigma = __fdiv_rn(span, 1.5f);
    const float denom = __fmul_rn(__fmul_rn(2.0f, sigma), sigma);  // (2*sigma)*sigma

    v4f xa = in4[fA], xb = in4[fB];
    float xs[8] = {xa.x, xa.y, xa.z, xa.w, xb.x, xb.y, xb.z, xb.w};
    float dv[8];
    #pragma unroll
    for (int j = 0; j < 8; ++j) {
        float d = __fsub_rn(xs[j], mu);
        float q = __fdiv_rn(__fmul_rn(d, d), denom);
        // correctly-rounded fp32 exp via double (matches np.exp float32)
        dv[j] = (float)exp(-(double)q);
    }

    float v[8]   = {0.f,0.f,0.f,0.f,0.f,0.f,0.f,0.f};
    float cnt[8] = {0.f,0.f,0.f,0.f,0.f,0.f,0.f,0.f};

    v4f* outp = (v4f*)out + (size_t)neuron * n4 + fA;
    const size_t tstride = (size_t)m * n4;

    #pragma unroll 4
    for (int t = 0; t < STEPN; ++t) {
        v4f sa, sb;
        #pragma unroll
        for (int j = 0; j < 4; ++j) {
            v[j] = __fadd_rn(v[j], dv[j]);
            float s = (v[j] >= VTH) ? 1.0f : 0.0f;
            v[j] = __fsub_rn(v[j], s * VTH);   // s*VTH exact (s in {0,1})
            sa[j] = s;
            cnt[j] += s;
        }
        #pragma unroll
        for (int j = 4; j < 8; ++j) {
            v[j] = __fadd_rn(v[j], dv[j]);
            float s = (v[j] >= VTH) ? 1.0f : 0.0f;
            v[j] = __fsub_rn(v[j], s * VTH);
            sb[j - 4] = s;
            cnt[j] += s;
        }
        outp[0]  = sa;
        outp[64] = sb;
        outp += tstride;
    }

    const float inv = 1.0f / (float)STEPN;   // exact
    v4f ra, rb;
    #pragma unroll
    for (int j = 0; j < 4; ++j) { ra[j] = cnt[j] * inv; rb[j] = cnt[j + 4] * inv; }
    outp[0]  = ra;
    outp[64] = rb;
}

extern "C" void kernel_launch(void* const* d_in, const int* in_sizes, int n_in,
                              void* d_out, int out_size, void* d_ws, size_t ws_size,
                              hipStream_t stream) {
    const float* inp = (const float*)d_in[0];
    const float* vth = (const float*)d_in[1];
    const int n_elem = in_sizes[0];                  // 262144
    const int m = out_size / ((STEPN + 1) * n_elem); // 10
    const int n4 = n_elem >> 2;                      // 65536

    unsigned* ws = (unsigned*)d_ws;
    float* out = (float*)d_out;

    const int rblocks = n4 / 256;                    // 256 partial blocks
    pe_minmax_part<<<rblocks, 256, 0, stream>>>((const v4f*)inp, ws);

    int total_threads = m * (n4 >> 7) * 64;          // 327680
    int mblocks = (total_threads + 255) / 256;       // 1280
    pe_main<<<mblocks, 256, 0, stream>>>((const v4f*)inp, ws, vth, out,
                                         n_elem, m, rblocks);
}

// Round 6
// 36.542 us; speedup vs baseline: 1.5267x; 1.0098x over previous
//
#include <hip/hip_runtime.h>
#include <math.h>

#define STEPN 16

typedef float v4f __attribute__((ext_vector_type(4)));

// ---- monotone key transform: uint min on keys == float min; max stored
// as inverted key so both partials reduce with min. No atomics anywhere.
__device__ __forceinline__ unsigned f2key(float f) {
    unsigned u = __float_as_uint(f);
    return u ^ ((u >> 31) ? 0xFFFFFFFFu : 0x80000000u);
}
__device__ __forceinline__ float key2f(unsigned k) {
    unsigned u = (k >> 31) ? (k ^ 0x80000000u) : ~k;
    return __uint_as_float(u);
}

// 64 blocks x 256 threads, 4 float4/thread. Per-block partial min / ~max
// written as plain stores -> no memset node, no atomics, deterministic.
__global__ __launch_bounds__(256) void pe_minmax_part(const v4f* __restrict__ in4,
                                                      unsigned* __restrict__ ws) {
    int gid = blockIdx.x * blockDim.x + threadIdx.x;
    unsigned kmin = 0xFFFFFFFFu, kimax = 0xFFFFFFFFu;
    #pragma unroll
    for (int r = 0; r < 4; ++r) {
        v4f v = in4[gid * 4 + r];
        unsigned a = f2key(v.x), b = f2key(v.y), c = f2key(v.z), d = f2key(v.w);
        kmin  = min(kmin,  min(min(a, b), min(c, d)));
        kimax = min(kimax, ~max(max(a, b), max(c, d)));
    }
    #pragma unroll
    for (int off = 32; off > 0; off >>= 1) {
        kmin  = min(kmin,  (unsigned)__shfl_down((int)kmin,  off, 64));
        kimax = min(kimax, (unsigned)__shfl_down((int)kimax, off, 64));
    }
    __shared__ unsigned sm[8];
    int lane = threadIdx.x & 63, wid = threadIdx.x >> 6;
    if (lane == 0) { sm[wid * 2] = kmin; sm[wid * 2 + 1] = kimax; }
    __syncthreads();
    if (threadIdx.x == 0) {
        unsigned a0 = sm[0], b0 = sm[1];
        #pragma unroll
        for (int w = 1; w < 4; ++w) { a0 = min(a0, sm[w * 2]); b0 = min(b0, sm[w * 2 + 1]); }
        ws[blockIdx.x * 2]     = a0;
        ws[blockIdx.x * 2 + 1] = b0;
    }
}

// 8 elements/thread, split-quad layout: lane i owns float4 (base+i) and
// (base+64+i) -> every store is 64 contiguous float4 = 1 KB.
// Grid = 1280 blocks = 20 waves/CU, fully resident.
// R6: phase-split — 4 exps -> quad-A store loop -> 4 exps -> quad-B loop,
// so the first store issues ~2x sooner and half the exp cost hides under
// the quad-A drain. Prologue: one wave reduces 64 partial pairs.
__global__ __launch_bounds__(256, 5) void pe_main(
        const v4f* __restrict__ in4,
        const unsigned* __restrict__ ws,
        const float* __restrict__ vth_p,
        float* __restrict__ out,
        int n_elem, int m)
{
    const int n4  = n_elem >> 2;        // float4 per plane (65536)
    const int wpp = n4 >> 7;            // waves per plane (512)
    const int gid  = blockIdx.x * blockDim.x + threadIdx.x;
    const int wave = gid >> 6;
    const int lane = gid & 63;
    const int neuron = wave / wpp;
    const int lw     = wave - neuron * wpp;
    const int fA = (lw << 7) + lane;
    const int fB = fA + 64;

    // Issue input loads first: HBM latency hides under the partial-reduce.
    v4f xa = in4[fA], xb = in4[fB];
    const float VTH = *vth_p;

    // ---- one wave reduces the 64 partial pairs, broadcasts via LDS ----
    __shared__ float sval[2];
    if (threadIdx.x < 64) {
        unsigned kmin  = ws[2 * threadIdx.x];
        unsigned kimax = ws[2 * threadIdx.x + 1];
        #pragma unroll
        for (int off = 32; off > 0; off >>= 1) {
            kmin  = min(kmin,  (unsigned)__shfl_down((int)kmin,  off, 64));
            kimax = min(kimax, (unsigned)__shfl_down((int)kimax, off, 64));
        }
        if (threadIdx.x == 0) {
            sval[0] = key2f(kmin);
            sval[1] = key2f(~kimax);
        }
    }
    __syncthreads();
    const float Imin = sval[0];
    const float Imax = sval[1];

    // Replicate numpy fp32 rounding exactly: no FMA contraction.
    const float span  = __fdiv_rn(__fsub_rn(Imax, Imin), (float)(m - 2));
    const float c     = (float)(2 * neuron - 3) * 0.5f;            // exact
    const float mu    = __fadd_rn(Imin, __fmul_rn(c, span));
    const float sigma = __fdiv_rn(span, 1.5f);
    const float denom = __fmul_rn(__fmul_rn(2.0f, sigma), sigma);  // (2*sigma)*sigma

    const size_t tstride = (size_t)m * n4;
    const float inv = 1.0f / (float)STEPN;   // exact

    // ---------- phase A: quad fA ----------
    {
        float xs[4] = {xa.x, xa.y, xa.z, xa.w};
        float dv[4];
        #pragma unroll
        for (int j = 0; j < 4; ++j) {
            float d = __fsub_rn(xs[j], mu);
            float q = __fdiv_rn(__fmul_rn(d, d), denom);
            dv[j] = (float)exp(-(double)q);   // correctly-rounded fp32 exp
        }
        float v[4]   = {0.f, 0.f, 0.f, 0.f};
        float cnt[4] = {0.f, 0.f, 0.f, 0.f};
        v4f* outp = (v4f*)out + (size_t)neuron * n4 + fA;
        #pragma unroll 4
        for (int t = 0; t < STEPN; ++t) {
            v4f sa;
            #pragma unroll
            for (int j = 0; j < 4; ++j) {
                v[j] = __fadd_rn(v[j], dv[j]);
                float s = (v[j] >= VTH) ? 1.0f : 0.0f;
                v[j] = __fsub_rn(v[j], s * VTH);   // exact: s in {0,1}
                sa[j] = s;
                cnt[j] += s;
            }
            *outp = sa;
            outp += tstride;
        }
        v4f ra = {cnt[0] * inv, cnt[1] * inv, cnt[2] * inv, cnt[3] * inv};
        *outp = ra;
    }

    // ---------- phase B: quad fB ----------
    {
        float xs[4] = {xb.x, xb.y, xb.z, xb.w};
        float dv[4];
        #pragma unroll
        for (int j = 0; j < 4; ++j) {
            float d = __fsub_rn(xs[j], mu);
            float q = __fdiv_rn(__fmul_rn(d, d), denom);
            dv[j] = (float)exp(-(double)q);
        }
        float v[4]   = {0.f, 0.f, 0.f, 0.f};
        float cnt[4] = {0.f, 0.f, 0.f, 0.f};
        v4f* outp = (v4f*)out + (size_t)neuron * n4 + fB;
        #pragma unroll 4
        for (int t = 0; t < STEPN; ++t) {
            v4f sb;
            #pragma unroll
            for (int j = 0; j < 4; ++j) {
                v[j] = __fadd_rn(v[j], dv[j]);
                float s = (v[j] >= VTH) ? 1.0f : 0.0f;
                v[j] = __fsub_rn(v[j], s * VTH);
                sb[j] = s;
                cnt[j] += s;
            }
            *outp = sb;
            outp += tstride;
        }
        v4f rb = {cnt[0] * inv, cnt[1] * inv, cnt[2] * inv, cnt[3] * inv};
        *outp = rb;
    }
}

extern "C" void kernel_launch(void* const* d_in, const int* in_sizes, int n_in,
                              void* d_out, int out_size, void* d_ws, size_t ws_size,
                              hipStream_t stream) {
    const float* inp = (const float*)d_in[0];
    const float* vth = (const float*)d_in[1];
    const int n_elem = in_sizes[0];                  // 262144
    const int m = out_size / ((STEPN + 1) * n_elem); // 10
    const int n4 = n_elem >> 2;                      // 65536

    unsigned* ws = (unsigned*)d_ws;
    float* out = (float*)d_out;

    const int rblocks = 64;                          // 64 partial pairs
    pe_minmax_part<<<rblocks, 256, 0, stream>>>((const v4f*)inp, ws);

    int total_threads = m * (n4 >> 7) * 64;          // 327680
    int mblocks = (total_threads + 255) / 256;       // 1280
    pe_main<<<mblocks, 256, 0, stream>>>((const v4f*)inp, ws, vth, out,
                                         n_elem, m);
}